// Round 5
// baseline (1765.246 us; speedup 1.0000x reference)
//
#include <hip/hip_runtime.h>
#include <hip/hip_bf16.h>
#include <stdint.h>

#define S_LEN 4096
#define HN    32
#define SSD   64
#define KD    2048      // D_IN = H*SS = D_OUT
#define MROWS 16384     // B*S

typedef __attribute__((ext_vector_type(4))) float f32x4;
typedef __attribute__((ext_vector_type(8))) short bf16x8;
typedef __attribute__((address_space(3))) char as3char;
typedef __attribute__((address_space(1))) char as1char;

__device__ __forceinline__ unsigned short f2bf(float f){
  unsigned int u = __float_as_uint(f);
  u += 0x7FFFu + ((u >> 16) & 1u);   // round-to-nearest-even
  return (unsigned short)(u >> 16);
}

// ---------------- convert f32 -> bf16 (for W_out) ----------------
__global__ __launch_bounds__(256) void cvt_bf16_k(const float* __restrict__ src,
                                                  unsigned short* __restrict__ dst){
  int i = (blockIdx.x * 256 + threadIdx.x) * 4;
  float4 v = *(const float4*)(src + i);
  ushort4 r;
  r.x = f2bf(v.x); r.y = f2bf(v.y); r.z = f2bf(v.z); r.w = f2bf(v.w);
  *(ushort4*)(dst + i) = r;
}

// ---------------- GEMM1: hx = x * W_in^T + bias (f32 src, reg-staged cvt) ----------------
__global__ __launch_bounds__(256) void gemm1_k(const float* __restrict__ A,   // x [MROWS][KD]
                                               const float* __restrict__ Bw,  // W_in [2048][KD]
                                               const float* __restrict__ bias,// [2048]
                                               float* __restrict__ C){        // hx [MROWS][2048]
  __shared__ short As[128*32];
  __shared__ short Bs[128*32];
  const int tid  = threadIdx.x;
  const int bn   = blockIdx.x & 15;
  const int bm   = blockIdx.x >> 4;
  const int lane = tid & 63;
  const int wv   = tid >> 6;
  const int wm   = (wv >> 1) * 64;
  const int wn   = (wv & 1) * 64;
  const int srow = tid >> 1;
  const int scol = (tid & 1) * 16;
  const float* aSrc = A  + (size_t)(bm*128 + srow)*KD + scol;
  const float* bSrc = Bw + (size_t)(bn*128 + srow)*KD + scol;

  f32x4 acc[4][4];
#pragma unroll
  for (int i=0;i<4;i++)
#pragma unroll
    for (int j=0;j<4;j++)
#pragma unroll
      for (int q=0;q<4;q++) acc[i][j][q] = 0.0f;

  float aR[16], bR[16];
#pragma unroll
  for (int i=0;i<4;i++){
    ((float4*)aR)[i] = *(const float4*)(aSrc + 4*i);
    ((float4*)bR)[i] = *(const float4*)(bSrc + 4*i);
  }

  const int fr  = lane & 15;
  const int fko = (lane >> 4) * 8;

  for (int kt=0; kt<KD/32; ++kt){
    // convert current tile (registers)
    bf16x8 a0, a1, b0, b1;
#pragma unroll
    for (int i=0;i<8;i++){
      a0[i] = (short)f2bf(aR[i]);   a1[i] = (short)f2bf(aR[8+i]);
      b0[i] = (short)f2bf(bR[i]);   b1[i] = (short)f2bf(bR[8+i]);
    }
    __syncthreads();                 // previous tile's frag reads done
    short* ap = &As[srow*32 + scol];
    short* bp = &Bs[srow*32 + scol];
    *(bf16x8*)ap     = a0; *(bf16x8*)(ap+8) = a1;
    *(bf16x8*)bp     = b0; *(bf16x8*)(bp+8) = b1;
    __syncthreads();
    if (kt + 1 < KD/32){             // prefetch next tile; overlaps MFMA below
#pragma unroll
      for (int i=0;i<4;i++){
        ((float4*)aR)[i] = *(const float4*)(aSrc + (kt+1)*32 + 4*i);
        ((float4*)bR)[i] = *(const float4*)(bSrc + (kt+1)*32 + 4*i);
      }
    }
    bf16x8 af[4], bq[4];
#pragma unroll
    for (int mt=0; mt<4; mt++) af[mt] = *(const bf16x8*)&As[(wm + mt*16 + fr)*32 + fko];
#pragma unroll
    for (int nt=0; nt<4; nt++) bq[nt] = *(const bf16x8*)&Bs[(wn + nt*16 + fr)*32 + fko];
#pragma unroll
    for (int mt=0; mt<4; mt++)
#pragma unroll
      for (int nt=0; nt<4; nt++)
        acc[mt][nt] = __builtin_amdgcn_mfma_f32_16x16x32_bf16(af[mt], bq[nt], acc[mt][nt], 0, 0, 0);
  }

  float bv[4];
#pragma unroll
  for (int nt=0; nt<4; nt++) bv[nt] = bias[bn*128 + wn + nt*16 + fr];
#pragma unroll
  for (int mt=0; mt<4; mt++)
#pragma unroll
    for (int nt=0; nt<4; nt++){
      const int col = bn*128 + wn + nt*16 + fr;
#pragma unroll
      for (int q=0; q<4; q++){
        const int row = bm*128 + wm + mt*16 + (lane>>4)*4 + q;
        C[(size_t)row*KD + col] = acc[mt][nt][q] + bv[nt];
      }
    }
}

// ---------------- scan: y_t = tanh(W_h y_{t-1} + hx_t) ----------------
// Register-resident: ONE wave per (b,h) chain; lane o owns y[o] and W row o
// (64 VGPRs). Broadcast of y[j] is v_readlane (compile-time lane index) ->
// SGPR consumed directly by v_fmac (1 SGPR read per VALU op is legal).
// Zero LDS hops, zero barriers on the serial chain; hx prefetch (8-deep)
// and ybf stores stay in flight.
__global__ __launch_bounds__(64) void scan_k(const float* __restrict__ hx,
                                             const float* __restrict__ sw,   // [32][64][64]
                                             const float* __restrict__ st0,  // [4][32][64]
                                             unsigned short* __restrict__ ybf){ // [MROWS][2048] bf16
  const int b = blockIdx.x >> 5, h = blockIdx.x & 31;
  const int lane = threadIdx.x;        // = output index o
  float w[64];
  const float* wr = sw + ((size_t)(h*64 + lane))*64;
#pragma unroll
  for (int i=0;i<16;i++) ((float4*)w)[i] = ((const float4*)wr)[i];

  float y = st0[(b*32 + h)*64 + lane];
  const float* hxp = hx + (size_t)b*S_LEN*KD + h*64 + lane;
  const size_t yo  = (size_t)b*S_LEN*KD + h*64 + lane;

  float hpre[8];
#pragma unroll
  for (int i=0;i<8;i++) hpre[i] = hxp[(size_t)i*KD];

#pragma unroll 8
  for (int t=0; t<S_LEN; ++t){
    const float hxv = hpre[t & 7];
    const int tn = (t + 8 < S_LEN) ? (t + 8) : (S_LEN - 1);
    hpre[t & 7] = hxp[(size_t)tn*KD];

    const int yi = __float_as_int(y);
    float a0=0.f, a1=0.f, a2=0.f, a3=0.f;
#pragma unroll
    for (int j=0;j<64;j+=4){
      a0 = fmaf(w[j+0], __int_as_float(__builtin_amdgcn_readlane(yi, j+0)), a0);
      a1 = fmaf(w[j+1], __int_as_float(__builtin_amdgcn_readlane(yi, j+1)), a1);
      a2 = fmaf(w[j+2], __int_as_float(__builtin_amdgcn_readlane(yi, j+2)), a2);
      a3 = fmaf(w[j+3], __int_as_float(__builtin_amdgcn_readlane(yi, j+3)), a3);
    }
    const float u = (a0 + a1) + (a2 + a3) + hxv;
    const float e = __expf(2.0f*u);
    y = 1.0f - 2.0f*__builtin_amdgcn_rcpf(e + 1.0f);   // tanh(u)
    ybf[yo + (size_t)t*KD] = f2bf(y);
  }
}

// ---------------- GEMM3: out = y * W_out^T (bf16 src, global_load_lds) ----------------
__global__ __launch_bounds__(256) void gemm3_k(const unsigned short* __restrict__ A,  // y bf16
                                               const unsigned short* __restrict__ Bw, // W_out bf16
                                               float* __restrict__ C){
  __shared__ short As[128*32];
  __shared__ short Bs[128*32];
  const int tid  = threadIdx.x;
  const int bn   = blockIdx.x & 15;
  const int bm   = blockIdx.x >> 4;
  const int lane = tid & 63;
  const int wv   = tid >> 6;
  const int wvU  = __builtin_amdgcn_readfirstlane(wv);
  const int wm   = (wv >> 1) * 64;
  const int wn   = (wv & 1) * 64;

  f32x4 acc[4][4];
#pragma unroll
  for (int i=0;i<4;i++)
#pragma unroll
    for (int j=0;j<4;j++)
#pragma unroll
      for (int q=0;q<4;q++) acc[i][j][q] = 0.0f;

  as3char* asB = (as3char*)As;
  as3char* bsB = (as3char*)Bs;
  as1char* aG  = (as1char*)A;
  as1char* bG  = (as1char*)Bw;

  const int fr  = lane & 15;
  const int fko = (lane >> 4) * 8;

  for (int kt=0; kt<KD/32; ++kt){
    __syncthreads();                 // previous tile's frag reads done
#pragma unroll
    for (int c=0;c<2;c++){
      const int off  = (wvU*2 + c)*1024 + lane*16;
      const int row  = off >> 6;
      const int colB = off & 63;
      __builtin_amdgcn_global_load_lds(
        (__attribute__((address_space(1))) void*)(aG + (size_t)(bm*128 + row)*4096 + (size_t)kt*64 + colB),
        (__attribute__((address_space(3))) void*)(asB + (wvU*2 + c)*1024),
        16, 0, 0);
      __builtin_amdgcn_global_load_lds(
        (__attribute__((address_space(1))) void*)(bG + (size_t)(bn*128 + row)*4096 + (size_t)kt*64 + colB),
        (__attribute__((address_space(3))) void*)(bsB + (wvU*2 + c)*1024),
        16, 0, 0);
    }
    __syncthreads();                 // loads landed (vmcnt drain at barrier)

    bf16x8 af[4], bq[4];
#pragma unroll
    for (int mt=0; mt<4; mt++) af[mt] = *(const bf16x8*)&As[(wm + mt*16 + fr)*32 + fko];
#pragma unroll
    for (int nt=0; nt<4; nt++) bq[nt] = *(const bf16x8*)&Bs[(wn + nt*16 + fr)*32 + fko];
#pragma unroll
    for (int mt=0; mt<4; mt++)
#pragma unroll
      for (int nt=0; nt<4; nt++)
        acc[mt][nt] = __builtin_amdgcn_mfma_f32_16x16x32_bf16(af[mt], bq[nt], acc[mt][nt], 0, 0, 0);
  }

#pragma unroll
  for (int mt=0; mt<4; mt++)
#pragma unroll
    for (int nt=0; nt<4; nt++){
      const int col = bn*128 + wn + nt*16 + fr;
#pragma unroll
      for (int q=0; q<4; q++){
        const int row = bm*128 + wm + mt*16 + (lane>>4)*4 + q;
        C[(size_t)row*KD + col] = acc[mt][nt][q];
      }
    }
}

extern "C" void kernel_launch(void* const* d_in, const int* in_sizes, int n_in,
                              void* d_out, int out_size, void* d_ws, size_t ws_size,
                              hipStream_t stream) {
  const float* x      = (const float*)d_in[0];
  const float* st0    = (const float*)d_in[1];
  const float* w_in   = (const float*)d_in[2];
  const float* w_st   = (const float*)d_in[3];
  const float* b_st   = (const float*)d_in[4];
  const float* w_out  = (const float*)d_in[5];
  float* out = (float*)d_out;

  // workspace: hx f32 (134MB) | y bf16 (67MB) | W_out bf16 (8MB) = 200 MiB
  const size_t HX_B = (size_t)MROWS * KD * 4;       // 134217728
  const size_t Y_B  = (size_t)MROWS * KD * 2;       // 67108864
  const size_t WO_B = (size_t)KD * KD * 2;          // 8388608
  if (ws_size < HX_B + Y_B + WO_B) return;          // fail loudly rather than corrupt
  char* ws = (char*)d_ws;
  float*          hx   = (float*)ws;
  unsigned short* ybf  = (unsigned short*)(ws + HX_B);
  unsigned short* wobf = (unsigned short*)(ws + HX_B + Y_B);

  cvt_bf16_k<<<dim3((KD*KD)/1024), dim3(256), 0, stream>>>(w_out, wobf);
  gemm1_k  <<<dim3((MROWS/128)*(KD/128)), dim3(256), 0, stream>>>(x, w_in, b_st, hx);
  scan_k   <<<dim3(128), dim3(64), 0, stream>>>(hx, w_st, st0, ybf);
  gemm3_k  <<<dim3((MROWS/128)*(KD/128)), dim3(256), 0, stream>>>(ybf, wobf, out);
}

// Round 6
// 1580.291 us; speedup vs baseline: 1.1170x; 1.1170x over previous
//
#include <hip/hip_runtime.h>
#include <hip/hip_bf16.h>
#include <stdint.h>

#define S_LEN 4096
#define HN    32
#define SSD   64
#define KD    2048      // D_IN = H*SS = D_OUT
#define MROWS 16384     // B*S

typedef __attribute__((ext_vector_type(4))) float f32x4;
typedef __attribute__((ext_vector_type(8))) short bf16x8;
typedef __attribute__((address_space(3))) char as3char;
typedef __attribute__((address_space(1))) char as1char;

__device__ __forceinline__ unsigned short f2bf(float f){
  unsigned int u = __float_as_uint(f);
  u += 0x7FFFu + ((u >> 16) & 1u);   // round-to-nearest-even
  return (unsigned short)(u >> 16);
}

// ---------------- convert f32 -> bf16 (vectorized, 4 elts/thread) ----------------
__global__ __launch_bounds__(256) void cvt_bf16_k(const float* __restrict__ src,
                                                  unsigned short* __restrict__ dst){
  int i = (blockIdx.x * 256 + threadIdx.x) * 4;
  float4 v = *(const float4*)(src + i);
  ushort4 r;
  r.x = f2bf(v.x); r.y = f2bf(v.y); r.z = f2bf(v.z); r.w = f2bf(v.w);
  *(ushort4*)(dst + i) = r;
}

// ---------------- GEMM (bf16, global_load_lds), optional bias epilogue ----------------
// C[row][col] = sum_k A[row][k]*B[col][k]  (+ bias[col] if bias != nullptr)
__global__ __launch_bounds__(256) void gemm_bf16_k(const unsigned short* __restrict__ A,
                                                   const unsigned short* __restrict__ Bw,
                                                   const float* __restrict__ bias,  // may be null
                                                   float* __restrict__ C){
  __shared__ short As[128*32];
  __shared__ short Bs[128*32];
  const int tid  = threadIdx.x;
  const int bn   = blockIdx.x & 15;
  const int bm   = blockIdx.x >> 4;
  const int lane = tid & 63;
  const int wv   = tid >> 6;
  const int wvU  = __builtin_amdgcn_readfirstlane(wv);
  const int wm   = (wv >> 1) * 64;
  const int wn   = (wv & 1) * 64;

  f32x4 acc[4][4];
#pragma unroll
  for (int i=0;i<4;i++)
#pragma unroll
    for (int j=0;j<4;j++)
#pragma unroll
      for (int q=0;q<4;q++) acc[i][j][q] = 0.0f;

  as3char* asB = (as3char*)As;
  as3char* bsB = (as3char*)Bs;
  as1char* aG  = (as1char*)A;
  as1char* bG  = (as1char*)Bw;

  const int fr  = lane & 15;
  const int fko = (lane >> 4) * 8;

  for (int kt=0; kt<KD/32; ++kt){
    __syncthreads();                 // previous tile's frag reads done
#pragma unroll
    for (int c=0;c<2;c++){
      const int off  = (wvU*2 + c)*1024 + lane*16;
      const int row  = off >> 6;
      const int colB = off & 63;
      __builtin_amdgcn_global_load_lds(
        (__attribute__((address_space(1))) void*)(aG + (size_t)(bm*128 + row)*4096 + (size_t)kt*64 + colB),
        (__attribute__((address_space(3))) void*)(asB + (wvU*2 + c)*1024),
        16, 0, 0);
      __builtin_amdgcn_global_load_lds(
        (__attribute__((address_space(1))) void*)(bG + (size_t)(bn*128 + row)*4096 + (size_t)kt*64 + colB),
        (__attribute__((address_space(3))) void*)(bsB + (wvU*2 + c)*1024),
        16, 0, 0);
    }
    __syncthreads();                 // loads landed (vmcnt drain at barrier)

    bf16x8 af[4], bq[4];
#pragma unroll
    for (int mt=0; mt<4; mt++) af[mt] = *(const bf16x8*)&As[(wm + mt*16 + fr)*32 + fko];
#pragma unroll
    for (int nt=0; nt<4; nt++) bq[nt] = *(const bf16x8*)&Bs[(wn + nt*16 + fr)*32 + fko];
#pragma unroll
    for (int mt=0; mt<4; mt++)
#pragma unroll
      for (int nt=0; nt<4; nt++)
        acc[mt][nt] = __builtin_amdgcn_mfma_f32_16x16x32_bf16(af[mt], bq[nt], acc[mt][nt], 0, 0, 0);
  }

  float bv[4] = {0.f, 0.f, 0.f, 0.f};
  if (bias){
#pragma unroll
    for (int nt=0; nt<4; nt++) bv[nt] = bias[bn*128 + wn + nt*16 + fr];
  }
#pragma unroll
  for (int mt=0; mt<4; mt++)
#pragma unroll
    for (int nt=0; nt<4; nt++){
      const int col = bn*128 + wn + nt*16 + fr;
#pragma unroll
      for (int q=0; q<4; q++){
        const int row = bm*128 + wm + mt*16 + (lane>>4)*4 + q;
        C[(size_t)row*KD + col] = acc[mt][nt][q] + bv[nt];
      }
    }
}

// ---------------- scan: y_t = tanh(W_h y_{t-1} + hx_t) ----------------
// Register-resident: ONE wave per (b,h) chain; lane o owns y[o] and W row o
// (64 VGPRs). Broadcast of y[j] is v_readlane (compile-time lane index) ->
// SGPR consumed directly by v_fmac. Zero LDS hops, zero barriers.
// __launch_bounds__(64, 1): min 1 wave/EU -> full VGPR budget (512). Without
// the ",1" the compiler capped VGPRs at ~48 and rematerialized w[] via global
// reloads every step (R5: 1218us, VGPR_Count=48).
__global__ __launch_bounds__(64, 1) void scan_k(const float* __restrict__ hx,
                                                const float* __restrict__ sw,   // [32][64][64]
                                                const float* __restrict__ st0,  // [4][32][64]
                                                unsigned short* __restrict__ ybf){ // [MROWS][2048] bf16
  const int b = blockIdx.x >> 5, h = blockIdx.x & 31;
  const int lane = threadIdx.x;        // = output index o
  float w[64];
  const float* wr = sw + ((size_t)(h*64 + lane))*64;
#pragma unroll
  for (int i=0;i<16;i++) ((float4*)w)[i] = ((const float4*)wr)[i];

  float y = st0[(b*32 + h)*64 + lane];
  const float* hxp = hx + (size_t)b*S_LEN*KD + h*64 + lane;
  const size_t yo  = (size_t)b*S_LEN*KD + h*64 + lane;

  float hpre[8];
#pragma unroll
  for (int i=0;i<8;i++) hpre[i] = hxp[(size_t)i*KD];

#pragma unroll 8
  for (int t=0; t<S_LEN; ++t){
    const float hxv = hpre[t & 7];
    const int tn = (t + 8 < S_LEN) ? (t + 8) : (S_LEN - 1);
    hpre[t & 7] = hxp[(size_t)tn*KD];

    const int yi = __float_as_int(y);
    float a0=0.f, a1=0.f, a2=0.f, a3=0.f;
#pragma unroll
    for (int j=0;j<64;j+=4){
      a0 = fmaf(w[j+0], __int_as_float(__builtin_amdgcn_readlane(yi, j+0)), a0);
      a1 = fmaf(w[j+1], __int_as_float(__builtin_amdgcn_readlane(yi, j+1)), a1);
      a2 = fmaf(w[j+2], __int_as_float(__builtin_amdgcn_readlane(yi, j+2)), a2);
      a3 = fmaf(w[j+3], __int_as_float(__builtin_amdgcn_readlane(yi, j+3)), a3);
    }
    const float u = (a0 + a1) + (a2 + a3) + hxv;
    const float e = __expf(2.0f*u);
    y = 1.0f - 2.0f*__builtin_amdgcn_rcpf(e + 1.0f);   // tanh(u)
    ybf[yo + (size_t)t*KD] = f2bf(y);
  }
}

extern "C" void kernel_launch(void* const* d_in, const int* in_sizes, int n_in,
                              void* d_out, int out_size, void* d_ws, size_t ws_size,
                              hipStream_t stream) {
  const float* x      = (const float*)d_in[0];
  const float* st0    = (const float*)d_in[1];
  const float* w_in   = (const float*)d_in[2];
  const float* w_st   = (const float*)d_in[3];
  const float* b_st   = (const float*)d_in[4];
  const float* w_out  = (const float*)d_in[5];
  float* out = (float*)d_out;

  // workspace layout (209 MiB total, regions time-shared):
  //   [0,            HX_B)        hx f32 (134MB)
  //   [HX_B,         HX_B+Y_B)    phase1: x_bf16 (67MB); phase2: y_bf16 (scan overwrites)
  //   [HX_B+Y_B,     +WO_B)       phase1: w_in_bf16 (8MB); phase2: w_out_bf16
  const size_t HX_B = (size_t)MROWS * KD * 4;       // 134217728
  const size_t Y_B  = (size_t)MROWS * KD * 2;       // 67108864
  const size_t WO_B = (size_t)KD * KD * 2;          // 8388608
  if (ws_size < HX_B + Y_B + WO_B) return;          // fail loudly rather than corrupt
  char* ws = (char*)d_ws;
  float*          hx   = (float*)ws;
  unsigned short* ybf  = (unsigned short*)(ws + HX_B);   // doubles as x_bf16
  unsigned short* wbf  = (unsigned short*)(ws + HX_B + Y_B); // w_in then w_out

  // phase 1: convert x and w_in, input GEMM (+bias)
  cvt_bf16_k<<<dim3((MROWS*(size_t)KD)/1024), dim3(256), 0, stream>>>(x, ybf);
  cvt_bf16_k<<<dim3((KD*KD)/1024), dim3(256), 0, stream>>>(w_in, wbf);
  gemm_bf16_k<<<dim3((MROWS/128)*(KD/128)), dim3(256), 0, stream>>>(ybf, wbf, b_st, hx);
  // phase 2: scan (overwrites x_bf16 region with y), then output GEMM
  scan_k<<<dim3(128), dim3(64), 0, stream>>>(hx, w_st, st0, ybf);
  cvt_bf16_k<<<dim3((KD*KD)/1024), dim3(256), 0, stream>>>(w_out, wbf);
  gemm_bf16_k<<<dim3((MROWS/128)*(KD/128)), dim3(256), 0, stream>>>(ybf, wbf, nullptr, out);
}